// Round 1
// baseline (1155.011 us; speedup 1.0000x reference)
//
#include <hip/hip_runtime.h>

// Problem constants (from reference): B=32, T=128, NQ=1000, NC=64, DK=128, DA=128
#define B_  32
#define T_  128
#define NC_ 64
#define HS  132   // h_f32 LDS row stride (floats)  -> (132%32)=4 banks/row step
#define HBS 136   // h_bf16 LDS row stride (ushorts) -> 272B rows, 16B aligned

typedef __attribute__((ext_vector_type(8))) short bf16x8;
typedef __attribute__((ext_vector_type(4))) float f32x4;

__device__ __forceinline__ float sigf(float x){ return __builtin_amdgcn_rcpf(1.f + __expf(-x)); }
__device__ __forceinline__ float tanh_f(float x){ return 2.f*__builtin_amdgcn_rcpf(1.f + __expf(-2.f*x)) - 1.f; }
__device__ __forceinline__ unsigned short f2b(float x){
  union { float f; unsigned int u; } v; v.f = x;
  return (unsigned short)((v.u + 0x7FFFu + ((v.u >> 16) & 1u)) >> 16);  // RNE bf16
}

// M=1 GEMV via 16x16x32 bf16 MFMA. vec: K bf16 in LDS; wrow: row j of [128][K]
// row-major bf16 weights (global). All lanes load the same vec chunk (rows 1..15
// of A are garbage broadcast -> only D row 0 is read). Valid result: lanes with
// (lane>>4)==0, acc[0] = out[j].
template<int NK>
__device__ __forceinline__ float gemv_m1(const unsigned short* __restrict__ vec,
                                         const unsigned short* __restrict__ wrow,
                                         int g){
  f32x4 acc = {0.f,0.f,0.f,0.f};
#pragma unroll
  for (int ks = 0; ks < NK; ++ks){
    bf16x8 a  = *(const bf16x8*)(vec  + ks*32 + 8*g);
    bf16x8 bb = *(const bf16x8*)(wrow + ks*32 + 8*g);
    acc = __builtin_amdgcn_mfma_f32_16x16x32_bf16(a, bb, acc, 0, 0, 0);
  }
  return acc[0];
}

// ---------------- stage: bf16 weight copies + a-part rowsum of W1 ----------------
__global__ __launch_bounds__(256) void stage_k(
    const float* __restrict__ W2, const float* __restrict__ W3,
    const float* __restrict__ W4, const float* __restrict__ W5,
    const float* __restrict__ W1,
    unsigned short* __restrict__ W2b, unsigned short* __restrict__ W3b,
    unsigned short* __restrict__ W4b, unsigned short* __restrict__ W5b,
    float* __restrict__ S)
{
  int i = blockIdx.x*256 + threadIdx.x;
  if (i < 128*384){ W2b[i] = f2b(W2[i]); W3b[i] = f2b(W3[i]); }
  if (i < 128*256){ W4b[i] = f2b(W4[i]); W5b[i] = f2b(W5[i]); }
  if (i < 128){
    float s = 0.f;
    const float* row = W1 + (size_t)i*256 + 128;
    for (int k = 0; k < 128; ++k) s += row[k];
    S[i] = s;   // sum_k W1[i][128+k]  (a_rep is constant along DA)
  }
}

// ---------------- prep: q_emb gather, qa GEMM (fp32 exact), pred[:,0]=0 ----------
__global__ __launch_bounds__(256) void prep_k(
    const int* __restrict__ qd, const float* __restrict__ ad,
    const float* __restrict__ qew, const float* __restrict__ W1,
    const float* __restrict__ b1, const float* __restrict__ S,
    float* __restrict__ oqe, float* __restrict__ oqa, float* __restrict__ pred)
{
  __shared__ float qe[16][128];
  __shared__ float w1c[128][65];
  const int tid = threadIdx.x;
  const int bt0 = blockIdx.x * 16;

  for (int i = tid; i < 16*128; i += 256){
    int r = i >> 7, d = i & 127;
    float v = qew[(size_t)qd[bt0 + r]*128 + d];
    qe[r][d] = v;
    oqe[(size_t)(bt0 + r)*128 + d] = v;
  }
  const int j = tid & 127, rh = tid >> 7;
  float accv[8];
  {
    float base = b1[j], Sj = S[j];
#pragma unroll
    for (int r = 0; r < 8; ++r) accv[r] = fmaf(ad[bt0 + rh*8 + r], Sj, base);
  }
  for (int c = 0; c < 2; ++c){
    __syncthreads();
    for (int i = tid; i < 128*64; i += 256){
      int jj = i >> 6, kk = i & 63;
      w1c[jj][kk] = W1[(size_t)jj*256 + c*64 + kk];
    }
    __syncthreads();
#pragma unroll 4
    for (int k = 0; k < 64; ++k){
      float wv = w1c[j][k];
#pragma unroll
      for (int r = 0; r < 8; ++r) accv[r] = fmaf(qe[rh*8 + r][c*64 + k], wv, accv[r]);
    }
  }
#pragma unroll
  for (int r = 0; r < 8; ++r) oqa[(size_t)(bt0 + rh*8 + r)*128 + j] = accv[r];
  if (blockIdx.x == 0 && tid < 32) pred[tid * T_] = 0.f;
}

// ---------------- recur: the 127-step recurrence, one block per batch ------------
struct __align__(16) Sm {
  float hf[64*HS];            // h state fp32
  float qe[3][64];            // qm rows, triple-buffered (t, t+1, t+2)
  float kp[128], rr[128], kcf[128], htl[128];
  float htp[4*128];           // h_tilde partials per M-tile
  float yv[128];
  float b2l[128], b3l[128], b4l[128], b5l[128];
  unsigned short hb[64*HBS];  // h state bf16 (MFMA A operand)
  unsigned short cat3[384];   // [learning_pre | learning | h_tilde_pre] bf16
  unsigned short kcb[128];    // KC bf16 (A' rows 128..255, broadcast)
  unsigned short ybuf[256];   // [qemb_next | h_tilde] bf16
};

__global__ __launch_bounds__(512) void recur_k(
    const int* __restrict__ qd, const float* __restrict__ qmx,
    const float* __restrict__ h0,
    const float* __restrict__ b2, const float* __restrict__ b3,
    const float* __restrict__ b4, const float* __restrict__ b5,
    const unsigned short* __restrict__ W2b, const unsigned short* __restrict__ W3b,
    const unsigned short* __restrict__ W4b, const unsigned short* __restrict__ W5b,
    const float* __restrict__ oqe, const float* __restrict__ oqa,
    float* __restrict__ H, float* __restrict__ pred)
{
  __shared__ Sm s;
  const int b   = blockIdx.x;
  const int tid = threadIdx.x;
  const int w = tid >> 6, lane = tid & 63, g = lane >> 4, li = lane & 15;
  const int mt = w & 3, nh = w >> 2;   // wave -> (M-tile, N-half) of the 64x128 GEMM

  // ---- init: h = broadcast(h0); H[0] = sigmoid(h0); biases; qm rows 0,1
  for (int i = tid; i < 64*128; i += 512){
    int n = i >> 7, d = i & 127;
    float v = h0[i];
    s.hf[n*HS + d] = v;
    s.hb[n*HBS + d] = f2b(v);
    H[(size_t)b*8192 + i] = sigf(v);
  }
  if (tid < 128){ s.b2l[tid]=b2[tid]; s.b3l[tid]=b3[tid]; s.b4l[tid]=b4[tid]; s.b5l[tid]=b5[tid]; }
  if (tid < 64){
    s.qe[0][tid] = qmx[(size_t)qd[b*T_    ]*64 + tid];
    s.qe[1][tid] = qmx[(size_t)qd[b*T_ + 1]*64 + tid];
  }
  __syncthreads();
  if (tid < 128){   // h_tilde0 + initial cat3 (learning_pre = 0, learning = qa[:,0])
    float acc = 0.f;
    for (int n = 0; n < 64; ++n) acc = fmaf(s.qe[0][n], s.hf[n*HS + tid], acc);
    s.htl[tid] = acc;
    s.cat3[tid]       = 0;
    s.cat3[128 + tid] = f2b(oqa[(size_t)b*T_*128 + tid]);
    s.cat3[256 + tid] = f2b(acc);
  }
  __syncthreads();

  for (int t = 0; t < T_-1; ++t){
    // prefetch next-row q_emb / qa into registers (consumed after ph1/at ph7)
    float qembv = 0.f, qav = 0.f;
    if (tid >= 128 && tid < 256) qembv = oqe[((size_t)b*T_ + t+1)*128 + (tid-128)];
    if (tid < 128)               qav   = oqa[((size_t)b*T_ + t+1)*128 + tid];
    int q2 = (t+2 < T_) ? qd[b*T_ + t+2] : 0;

    // ph1: KP/R GEMVs (wave w owns output tile j in [16w,16w+16) for both W2,W3)
    {
      const unsigned short* w2row = W2b + (size_t)(w*16 + li)*384;
      const unsigned short* w3row = W3b + (size_t)(w*16 + li)*384;
      float o2 = gemv_m1<12>(s.cat3, w2row, g);
      float o3 = gemv_m1<12>(s.cat3, w3row, g);
      if (g == 0){
        int jj = w*16 + li;
        s.kp[jj] = tanh_f(o2 + s.b2l[jj]);
        s.rr[jj] = sigf (o3 + s.b3l[jj]);
      }
    }
    __syncthreads();                       // B1
    // ph2: KC; ybuf low; prefetch qm row t+2 into slot (t+2)%3
    if (tid < 128){
      float kc = s.rr[tid]*(s.kp[tid] + 1.f)*0.5f;
      s.kcf[tid] = kc; s.kcb[tid] = f2b(kc);
    } else if (tid < 256){
      s.ybuf[tid-128] = f2b(qembv);
    } else if (tid < 320){
      if (t+2 < T_) s.qe[(t+2)%3][tid-256] = qmx[(size_t)q2*64 + (tid-256)];
    }
    __syncthreads();                       // B2
    // ph4: z = [h_pre | KC] @ W4^T + b4 ; h = qe*KC + sig(z)*h_pre ; H[t+1] ; ht partials
    {
      bf16x8 af[8];
#pragma unroll
      for (int ks = 0; ks < 4; ++ks) af[ks]   = *(const bf16x8*)&s.hb[(mt*16 + li)*HBS + ks*32 + 8*g];
#pragma unroll
      for (int ks = 0; ks < 4; ++ks) af[4+ks] = *(const bf16x8*)&s.kcb[ks*32 + 8*g];  // KC rows (broadcast)
      float qc[4], qn[4];
#pragma unroll
      for (int r = 0; r < 4; ++r){
        int n = mt*16 + g*4 + r;
        qc[r] = s.qe[t%3][n];       // q_e (current)
        qn[r] = s.qe[(t+1)%3][n];   // q_e_next
      }
      __syncthreads();                     // B3: all h reads done before h writes
#pragma unroll
      for (int nt4 = 0; nt4 < 4; ++nt4){
        int nt = nh*4 + nt4;
        int j  = nt*16 + li;
        f32x4 acc = {0.f,0.f,0.f,0.f};
        const unsigned short* wr = W4b + (size_t)j*256;
#pragma unroll
        for (int ks = 0; ks < 8; ++ks){
          bf16x8 bb = *(const bf16x8*)(wr + ks*32 + 8*g);
          acc = __builtin_amdgcn_mfma_f32_16x16x32_bf16(af[ks], bb, acc, 0, 0, 0);
        }
        float kcj = s.kcf[j], b4j = s.b4l[j];
        float part = 0.f;
#pragma unroll
        for (int r = 0; r < 4; ++r){
          int n = mt*16 + g*4 + r;            // C/D: row=(lane>>4)*4+r, col=lane&15
          float sg = sigf(acc[r] + b4j);
          float hp = s.hf[n*HS + j];
          float hn = fmaf(qc[r], kcj, sg*hp);
          s.hf[n*HS + j] = hn;
          s.hb[n*HBS + j] = f2b(hn);
          if (t < T_-2) H[((size_t)(t+1)*B_ + b)*8192 + n*128 + j] = sigf(hn);
          part = fmaf(qn[r], hn, part);
        }
        part += __shfl_xor(part, 16);
        part += __shfl_xor(part, 32);
        if (g == 0) s.htp[mt*128 + j] = part;
      }
    }
    __syncthreads();                       // B4
    // ph5: h_tilde reduce + ybuf high
    if (tid < 128){
      float ht = s.htp[tid] + s.htp[128+tid] + s.htp[256+tid] + s.htp[384+tid];
      s.htl[tid] = ht;
      s.ybuf[128 + tid] = f2b(ht);
    }
    __syncthreads();                       // B5
    // ph6: y GEMV ; ph7: cat3 shift + qm-slot rotation happens implicitly (triple buffer)
    {
      const unsigned short* w5row = W5b + (size_t)(w*16 + li)*256;
      float o5 = gemv_m1<8>(s.ybuf, w5row, g);
      if (g == 0){
        int jj = w*16 + li;
        s.yv[jj] = sigf(o5 + s.b5l[jj]);
      }
    }
    if (tid < 128){
      unsigned short cur = s.cat3[128 + tid];   // learning -> learning_pre
      s.cat3[tid]       = cur;
      s.cat3[128 + tid] = f2b(qav);             // qa[b, t+1]
      s.cat3[256 + tid] = f2b(s.htl[tid]);      // h_tilde -> h_tilde_pre
    }
    __syncthreads();                       // B6
    if (w == 0){                           // y reduce -> pred[b, t+1]
      float v = s.yv[lane] + s.yv[64 + lane];
      v += __shfl_down(v, 32); v += __shfl_down(v, 16); v += __shfl_down(v, 8);
      v += __shfl_down(v, 4);  v += __shfl_down(v, 2);  v += __shfl_down(v, 1);
      if (lane == 0) pred[b*T_ + t + 1] = v * (1.f/128.f);
    }
  }
}

extern "C" void kernel_launch(void* const* d_in, const int* in_sizes, int n_in,
                              void* d_out, int out_size, void* d_ws, size_t ws_size,
                              hipStream_t stream)
{
  const int*   qd  = (const int*)  d_in[0];
  const float* ad  = (const float*)d_in[1];
  const float* qmx = (const float*)d_in[2];
  const float* qew = (const float*)d_in[3];
  const float* W1  = (const float*)d_in[4];
  const float* b1  = (const float*)d_in[5];
  const float* W2  = (const float*)d_in[6];
  const float* b2  = (const float*)d_in[7];
  const float* W3  = (const float*)d_in[8];
  const float* b3  = (const float*)d_in[9];
  const float* W4  = (const float*)d_in[10];
  const float* b4  = (const float*)d_in[11];
  const float* W5  = (const float*)d_in[12];
  const float* b5  = (const float*)d_in[13];
  const float* h0  = (const float*)d_in[14];

  float* H    = (float*)d_out;                         // [127][32][64][128]
  float* pred = H   + (size_t)127*32*64*128;           // [32][128]
  float* oqe  = pred + (size_t)32*128;                 // [32][128][128]
  float* oqa  = oqe + (size_t)32*128*128;              // [32][128][128]

  unsigned short* W2b = (unsigned short*)d_ws;         // [128][384] bf16
  unsigned short* W3b = W2b + 128*384;
  unsigned short* W4b = W3b + 128*384;                 // [128][256] bf16 (W4a|W4b)
  unsigned short* W5b = W4b + 128*256;                 // [128][256] bf16
  float*          S   = (float*)(W5b + 128*256);       // [128] fp32 rowsums of W1[:,128:]

  stage_k<<<192, 256, 0, stream>>>(W2, W3, W4, W5, W1, W2b, W3b, W4b, W5b, S);
  prep_k <<<256, 256, 0, stream>>>(qd, ad, qew, W1, b1, S, oqe, oqa, pred);
  recur_k<<<32,  512, 0, stream>>>(qd, qmx, h0, b2, b3, b4, b5,
                                   W2b, W3b, W4b, W5b, oqe, oqa, H, pred);
}